// Round 1
// baseline (413.594 us; speedup 1.0000x reference)
//
#include <hip/hip_runtime.h>

#define B_ 8
#define K_ 8
#define C_ 256
#define L_ 4096
#define TOPK_ 4
#define BN 64
#define BK 32
#define LDST 40   // LDS row stride (elems): 32 data + 8 pad -> 80B rows, 16B aligned, conflict-free

typedef __attribute__((ext_vector_type(8))) short bf16x8;
typedef __attribute__((ext_vector_type(4))) float f32x4;

union P8 { bf16x8 v; unsigned short s[8]; };
union F4 { float4 v; float f[4]; };

__device__ __forceinline__ unsigned short f2bf(float x) {
  unsigned u = __float_as_uint(x);
  u += 0x7fffu + ((u >> 16) & 1u);   // RNE; inputs are finite (no NaN path needed)
  return (unsigned short)(u >> 16);
}

// ---- Kernel 1: hard top-k routing (matches jax.lax.top_k tie-break: lowest index) ----
__global__ void route_kernel(const float* __restrict__ scores,
                             float* __restrict__ wts,
                             int* __restrict__ sel) {
  int b = threadIdx.x;
  if (b < B_) {
    float s[K_];
#pragma unroll
    for (int k = 0; k < K_; ++k) s[k] = scores[b * K_ + k];
    float tw[TOPK_]; int ch[TOPK_];
    float sum = 0.f;
#pragma unroll
    for (int i = 0; i < TOPK_; ++i) {
      float bv = -1e30f; int bk = 0;
#pragma unroll
      for (int k = 0; k < K_; ++k) {
        if (s[k] > bv) { bv = s[k]; bk = k; }   // strict > keeps lowest index on ties
      }
      ch[i] = bk; tw[i] = bv; sum += bv;
      s[bk] = -1e30f;
    }
    float inv = 1.f / (sum + 1e-8f);
#pragma unroll
    for (int i = 0; i < TOPK_; ++i) {
      wts[b * TOPK_ + i] = tw[i] * inv;
      sel[b * TOPK_ + i] = ch[i];
    }
  }
}

// ---- Kernel 2: fused selected-expert GEMM + weighted combine + bias ----
// Block: 256 thr (4 waves). Tile: BM=256 (all d), BN=64 (l), BK=32 (c).
// Wave w computes d in [64w, 64w+64) x full BN via 4x4 of 16x16x32 bf16 MFMA.
// A = EW[k] (d x c), B = w[b,k]*xs[b,k] (c x l, transposed into LDS [l][c]).
__global__ __launch_bounds__(256, 2)
void moe_main(const float* __restrict__ xs, const float* __restrict__ ew,
              const float* __restrict__ eb, const float* __restrict__ wts,
              const int* __restrict__ sel, float* __restrict__ out) {
  __shared__ alignas(16) unsigned short As[C_ * LDST];   // [d][c] 20 KB
  __shared__ alignas(16) unsigned short Bs[BN * LDST];   // [l][c]  5 KB
  __shared__ float biasc[C_];

  const int t = threadIdx.x;
  const int b = blockIdx.y;
  const int l0 = blockIdx.x * BN;
  const int wave = t >> 6;
  const int lane = t & 63;
  const int l16 = lane & 15;
  const int quad = lane >> 4;
  const int cb = (t >> 4) * 8;     // B-stage: c sub-block (t<64 only)
  const int loff = (t & 15) * 4;   // B-stage: l sub-block (t<64 only)

  float w_s[TOPK_]; int k_s[TOPK_];
#pragma unroll
  for (int i = 0; i < TOPK_; ++i) {
    w_s[i] = wts[b * TOPK_ + i];
    k_s[i] = sel[b * TOPK_ + i];
  }

  {  // combined bias: biasc[d] = sum_s w_s * eb[k_s][d]
    float a = 0.f;
#pragma unroll
    for (int i = 0; i < TOPK_; ++i) a += w_s[i] * eb[k_s[i] * C_ + t];
    biasc[t] = a;
  }

  f32x4 acc[4][4];
#pragma unroll
  for (int mi = 0; mi < 4; ++mi)
#pragma unroll
    for (int ni = 0; ni < 4; ++ni)
      acc[mi][ni] = (f32x4){0.f, 0.f, 0.f, 0.f};

  F4 ar[8], br[8];  // prefetch registers

  auto issue_loads = [&](int slot, int c0) {
    // A: thread t owns d-row t: EW[k][t][c0..c0+32) as 8 float4
    const float* ewk = ew + (size_t)k_s[slot] * C_ * C_ + (size_t)t * C_ + c0;
#pragma unroll
    for (int j = 0; j < 8; ++j) ar[j].v = ((const float4*)ewk)[j];
    // B: wave 0 only: thread t owns 8 c-rows x 4 l: xs[b][k][c0+cb+j][l0+loff..+4)
    if (t < 64) {
      const float* xp = xs + (((size_t)b * K_ + k_s[slot]) * C_ + (size_t)(c0 + cb)) * L_ + l0 + loff;
#pragma unroll
      for (int j = 0; j < 8; ++j) br[j].v = *(const float4*)(xp + (size_t)j * L_);
    }
  };

  issue_loads(0, 0);

  for (int step = 0; step < 32; ++step) {   // 4 slots x 8 c-steps
    __syncthreads();
    {  // write prefetched regs -> LDS (fp32 -> bf16; weight folded into B)
      unsigned short* arow = As + t * LDST;
#pragma unroll
      for (int g = 0; g < 4; ++g) {
        P8 p;
#pragma unroll
        for (int e = 0; e < 4; ++e) {
          p.s[e]     = f2bf(ar[2 * g].f[e]);
          p.s[4 + e] = f2bf(ar[2 * g + 1].f[e]);
        }
        *(bf16x8*)(arow + g * 8) = p.v;
      }
      if (t < 64) {
        float w = w_s[step >> 3];
#pragma unroll
        for (int i = 0; i < 4; ++i) {
          P8 p;
#pragma unroll
          for (int j = 0; j < 8; ++j) p.s[j] = f2bf(w * br[j].f[i]);
          *(bf16x8*)(Bs + (size_t)(loff + i) * LDST + cb) = p.v;
        }
      }
    }
    __syncthreads();
    if (step + 1 < 32) issue_loads((step + 1) >> 3, ((step + 1) & 7) * BK);

    bf16x8 af[4], bfr[4];
#pragma unroll
    for (int mi = 0; mi < 4; ++mi)
      af[mi] = *(const bf16x8*)(As + (size_t)(wave * 64 + mi * 16 + l16) * LDST + quad * 8);
#pragma unroll
    for (int ni = 0; ni < 4; ++ni)
      bfr[ni] = *(const bf16x8*)(Bs + (size_t)(ni * 16 + l16) * LDST + quad * 8);
#pragma unroll
    for (int mi = 0; mi < 4; ++mi)
#pragma unroll
      for (int ni = 0; ni < 4; ++ni)
        acc[mi][ni] = __builtin_amdgcn_mfma_f32_16x16x32_bf16(af[mi], bfr[ni], acc[mi][ni], 0, 0, 0);
  }

  // epilogue: D[m][n] layout col=lane&15, row=quad*4+reg
#pragma unroll
  for (int mi = 0; mi < 4; ++mi) {
#pragma unroll
    for (int r = 0; r < 4; ++r) {
      int d = wave * 64 + mi * 16 + quad * 4 + r;
      float bias = biasc[d];
#pragma unroll
      for (int ni = 0; ni < 4; ++ni) {
        out[((size_t)b * C_ + d) * L_ + l0 + ni * 16 + l16] = acc[mi][ni][r] + bias;
      }
    }
  }
}

extern "C" void kernel_launch(void* const* d_in, const int* in_sizes, int n_in,
                              void* d_out, int out_size, void* d_ws, size_t ws_size,
                              hipStream_t stream) {
  const float* xs     = (const float*)d_in[0];
  const float* scores = (const float*)d_in[1];
  const float* ew     = (const float*)d_in[2];
  const float* eb     = (const float*)d_in[3];
  float* out = (float*)d_out;

  float* wts = (float*)d_ws;                    // B_*TOPK_ floats
  int*   sel = (int*)((char*)d_ws + 256);       // B_*TOPK_ ints

  route_kernel<<<1, 64, 0, stream>>>(scores, wts, sel);
  dim3 grid(L_ / BN, B_);
  moe_main<<<grid, 256, 0, stream>>>(xs, ew, eb, wts, sel, out);
}

// Round 2
// 348.457 us; speedup vs baseline: 1.1869x; 1.1869x over previous
//
#include <hip/hip_runtime.h>

#define B_ 8
#define K_ 8
#define C_ 256
#define L_ 4096
#define TOPK_ 4
#define BN 128
#define BK 32
#define LDST 40   // LDS row stride (bf16 elems): 32 data + 8 pad; 80 B rows, 16B-aligned

typedef __attribute__((ext_vector_type(8))) short bf16x8;
typedef __attribute__((ext_vector_type(4))) float f32x4;

union P8 { bf16x8 v; unsigned short s[8]; };
union F4 { float4 v; float f[4]; };

__device__ __forceinline__ unsigned short f2bf(float x) {
  unsigned u = __float_as_uint(x);
  u += 0x7fffu + ((u >> 16) & 1u);   // RNE; inputs finite
  return (unsigned short)(u >> 16);
}

// top-k routing, matches jax.lax.top_k tie-break (lowest index wins via strict >)
__device__ __forceinline__ void route_b(const float* __restrict__ scores, int b,
                                        float w[TOPK_], int kk[TOPK_]) {
  float s[K_];
#pragma unroll
  for (int k = 0; k < K_; ++k) s[k] = scores[b * K_ + k];
  float sum = 0.f;
#pragma unroll
  for (int i = 0; i < TOPK_; ++i) {
    float bv = -1e30f; int bk = 0;
#pragma unroll
    for (int k = 0; k < K_; ++k)
      if (s[k] > bv) { bv = s[k]; bk = k; }
    kk[i] = bk; w[i] = bv; sum += bv;
    s[bk] = -1e30f;
  }
  float inv = 1.f / (sum + 1e-8f);
#pragma unroll
  for (int i = 0; i < TOPK_; ++i) w[i] *= inv;
}

// ---- Prepass: route + fold w into EW (fp32 -> bf16, tiled) + combined bias ----
// grid = 32 blocks (b*4+i), 256 threads.
// EWb tiled layout: [b][i][cb(8)][d(256)][ci(32)] so the main kernel's per-step
// A-tile (16 KB) is one fully-contiguous, coalesced chunk.
__global__ __launch_bounds__(256)
void prep_kernel(const float* __restrict__ scores, const float* __restrict__ ew,
                 const float* __restrict__ eb, int* __restrict__ sel,
                 float* __restrict__ biasc, unsigned short* __restrict__ ewb) {
  const int blk = blockIdx.x;
  const int b = blk >> 2, i = blk & 3;
  const int t = threadIdx.x;
  float w[TOPK_]; int kk[TOPK_];
  route_b(scores, b, w, kk);
  if (i == 0) {
    if (t < TOPK_) sel[b * TOPK_ + t] = kk[t];
    float a = 0.f;
#pragma unroll
    for (int j = 0; j < TOPK_; ++j) a += w[j] * eb[kk[j] * C_ + t];
    biasc[b * C_ + t] = a;
  }
  const float wi = w[i];
  const float* src = ew + (size_t)kk[i] * C_ * C_;
  unsigned short* dst = ewb + (size_t)blk * (C_ * C_);
  // chunk m in [0,8192): flat bf16 index m*8; d=(m>>2)&255, cb=m>>10, ci=(m&3)*8
  for (int j = 0; j < 32; ++j) {
    int m = t + 256 * j;
    int d = (m >> 2) & 255;
    int cb = m >> 10;
    int ci = (m & 3) * 8;
    const float* sp = src + d * C_ + cb * 32 + ci;
    F4 a0, a1; a0.v = *(const float4*)sp; a1.v = *(const float4*)(sp + 4);
    P8 p;
#pragma unroll
    for (int e = 0; e < 4; ++e) { p.s[e] = f2bf(wi * a0.f[e]); p.s[4 + e] = f2bf(wi * a1.f[e]); }
    *(bf16x8*)(dst + (size_t)m * 8) = p.v;
  }
}

// ---- Main: selected-expert GEMM, double-buffered LDS, one barrier/step ----
// Block: 256 thr (4 waves). Tile: BM=256 (all d), BN=128 (l), BK=32 (c).
// Wave w: d in [64w,64w+64) x 128 l via 4x8 of 16x16x32 bf16 MFMA.
__global__ __launch_bounds__(256, 1)
void moe_main(const float* __restrict__ xs, const unsigned short* __restrict__ ewb,
              const float* __restrict__ biasc, const int* __restrict__ sel,
              float* __restrict__ out) {
  __shared__ alignas(16) unsigned short As[2][C_ * LDST];   // 20 KB x2
  __shared__ alignas(16) unsigned short Bs[2][BN * LDST];   // 10 KB x2

  const int t = threadIdx.x;
  const int b = blockIdx.y;
  const int l0 = blockIdx.x * BN;
  const int wave = t >> 6;
  const int lane = t & 63;
  const int l16 = lane & 15;
  const int quad = lane >> 4;
  // B staging: thread owns c in [cq,cq+4), l in [lq,lq+4)
  const int lq = (t & 31) * 4;
  const int cq = (t >> 5) * 4;

  int k_s[TOPK_];
#pragma unroll
  for (int i = 0; i < TOPK_; ++i) k_s[i] = sel[b * TOPK_ + i];

  f32x4 acc[4][8];
#pragma unroll
  for (int mi = 0; mi < 4; ++mi)
#pragma unroll
    for (int ni = 0; ni < 8; ++ni)
      acc[mi][ni] = (f32x4){0.f, 0.f, 0.f, 0.f};

  const unsigned short* ewb_b = ewb + (size_t)b * TOPK_ * (C_ * C_);

  bf16x8 ar[4]; F4 br[4];
  auto issue = [&](int s) {
    const int slot = s >> 3, cb = s & 7;
    const unsigned short* ap = ewb_b + (size_t)slot * (C_ * C_) + cb * 8192 + t * 32;
#pragma unroll
    for (int j = 0; j < 4; ++j) ar[j] = *(const bf16x8*)(ap + j * 8);
    const float* xp = xs + (((size_t)b * K_ + k_s[slot]) * C_ + (size_t)(cb * 32 + cq)) * L_ + l0 + lq;
#pragma unroll
    for (int j = 0; j < 4; ++j) br[j].v = *(const float4*)(xp + (size_t)j * L_);
  };

  issue(0);
  for (int s = 0; s < 32; ++s) {   // 4 slots x 8 c-steps
    const int buf = s & 1;
    {  // staged regs -> LDS buf (A already bf16; B: fp32->bf16 + transpose)
      unsigned short* arow = As[buf] + t * LDST;
#pragma unroll
      for (int j = 0; j < 4; ++j) *(bf16x8*)(arow + j * 8) = ar[j];
#pragma unroll
      for (int i2 = 0; i2 < 4; ++i2) {
        union { unsigned short s4[4]; unsigned long long u; } p;
#pragma unroll
        for (int j = 0; j < 4; ++j) p.s4[j] = f2bf(br[j].f[i2]);
        *(unsigned long long*)(Bs[buf] + (size_t)(lq + i2) * LDST + cq) = p.u;
      }
    }
    if (s + 1 < 32) issue(s + 1);   // prefetch next step into regs
    __syncthreads();                // buf complete; also fences buf reuse (s-2 readers done)

    bf16x8 af[4], bfr[8];
#pragma unroll
    for (int mi = 0; mi < 4; ++mi)
      af[mi] = *(const bf16x8*)(As[buf] + (size_t)(wave * 64 + mi * 16 + l16) * LDST + quad * 8);
#pragma unroll
    for (int ni = 0; ni < 8; ++ni)
      bfr[ni] = *(const bf16x8*)(Bs[buf] + (size_t)(ni * 16 + l16) * LDST + quad * 8);
#pragma unroll
    for (int mi = 0; mi < 4; ++mi)
#pragma unroll
      for (int ni = 0; ni < 8; ++ni)
        acc[mi][ni] = __builtin_amdgcn_mfma_f32_16x16x32_bf16(af[mi], bfr[ni], acc[mi][ni], 0, 0, 0);
  }

  // epilogue: C/D layout col=lane&15 (l), row=quad*4+r (d)
  const float* bc = biasc + b * C_;
#pragma unroll
  for (int mi = 0; mi < 4; ++mi) {
#pragma unroll
    for (int r = 0; r < 4; ++r) {
      const int d = wave * 64 + mi * 16 + quad * 4 + r;
      const float bias = bc[d];
      float* orow = out + ((size_t)b * C_ + d) * L_ + l0;
#pragma unroll
      for (int ni = 0; ni < 8; ++ni)
        orow[ni * 16 + l16] = acc[mi][ni][r] + bias;
    }
  }
}

extern "C" void kernel_launch(void* const* d_in, const int* in_sizes, int n_in,
                              void* d_out, int out_size, void* d_ws, size_t ws_size,
                              hipStream_t stream) {
  const float* xs     = (const float*)d_in[0];
  const float* scores = (const float*)d_in[1];
  const float* ew     = (const float*)d_in[2];
  const float* eb     = (const float*)d_in[3];
  float* out = (float*)d_out;

  int*   sel   = (int*)d_ws;                                // 32 ints
  float* biasc = (float*)((char*)d_ws + 1024);              // 8*256 f32
  unsigned short* ewb = (unsigned short*)((char*)d_ws + 16384);  // 4 MB bf16

  prep_kernel<<<B_ * TOPK_, 256, 0, stream>>>(scores, ew, eb, sel, biasc, ewb);
  dim3 grid(L_ / BN, B_);
  moe_main<<<grid, 256, 0, stream>>>(xs, ewb, biasc, sel, out);
}